// Round 10
// baseline (188.528 us; speedup 1.0000x reference)
//
#include <hip/hip_runtime.h>
#include <hip/hip_bf16.h>

typedef unsigned short u16;

#define B_    4
#define T_    4096
#define C_    512
#define H_    8
#define D_    64
#define WIN_  15
#define PAD_  7
#define M_    (B_*T_)      // 16384 rows
#define NQKV  1536
#define KDIM  512

typedef __bf16 bf16x8 __attribute__((ext_vector_type(8)));
typedef float  f32x4  __attribute__((ext_vector_type(4)));

__device__ __forceinline__ u16 f2bf(float f) {
    union { float f; unsigned int i; } c; c.f = f;
    unsigned int lsb = (c.i >> 16) & 1u;
    c.i += 0x7fffu + lsb;                 // round-to-nearest-even
    return (u16)(c.i >> 16);
}
__device__ __forceinline__ float bf2f(u16 u) {
    union { unsigned int i; float f; } c; c.i = ((unsigned int)u) << 16; return c.f;
}

// global->LDS direct DMA, 16B per lane, dest = wave-uniform base + lane*16
__device__ __forceinline__ void gll16(const void* g, void* l) {
    __builtin_amdgcn_global_load_lds(
        (const __attribute__((address_space(1))) void*)g,
        (__attribute__((address_space(3))) void*)l, 16, 0, 0);
}

// ---------------------------------------------------------------------------
// R20 prep = apply_mask (blocks [0,4096)) + pack (blocks [4096,4352)).
// ---------------------------------------------------------------------------
__global__ __launch_bounds__(256) void prep(
    const float* __restrict__ x, const float* __restrict__ mask,
    u16* __restrict__ xm,
    const float* __restrict__ Wq, const float* __restrict__ Wkv,
    const float* __restrict__ Wp,
    u16* __restrict__ Wt_qkv, u16* __restrict__ Wpt)
{
    __shared__ float tile[64][65];
    const int bid = blockIdx.x;
    if (bid < 4096) {
        int idx = bid * 256 + threadIdx.x;
        int e0 = idx * 8;
        float mval = mask[e0 >> 9];
        float4 a = *(const float4*)(x + e0);
        float4 b = *(const float4*)(x + e0 + 4);
        union { uint4 u; u16 s[8]; } o;
        o.s[0] = f2bf(a.x * mval); o.s[1] = f2bf(a.y * mval);
        o.s[2] = f2bf(a.z * mval); o.s[3] = f2bf(a.w * mval);
        o.s[4] = f2bf(b.x * mval); o.s[5] = f2bf(b.y * mval);
        o.s[6] = f2bf(b.z * mval); o.s[7] = f2bf(b.w * mval);
        *(uint4*)(xm + e0) = o.u;
        return;
    }
    const int pb = bid - 4096;
    const float* src; int srcld; u16* dst; int n0, k0;
    if (pb < 192) {
        n0 = (pb % 24) * 64; k0 = (pb / 24) * 64;
        dst = Wt_qkv;
        if (n0 < 512) { src = Wq + n0;          srcld = 512;  }
        else          { src = Wkv + (n0 - 512); srcld = 1024; }
    } else {
        const int b2 = pb - 192;
        n0 = (b2 % 8) * 64; k0 = (b2 / 8) * 64;
        dst = Wpt; src = Wp + n0; srcld = 512;
    }
    const int tr = threadIdx.x >> 6;
    const int tc = threadIdx.x & 63;
    #pragma unroll
    for (int p = 0; p < 16; p++) {
        const int kk = p * 4 + tr;
        tile[kk][tc] = src[(size_t)(k0 + kk) * srcld + tc];
    }
    __syncthreads();
    #pragma unroll
    for (int p = 0; p < 16; p++) {
        const int nn = p * 4 + tr;
        dst[(size_t)(n0 + nn) * 512 + k0 + tc] = f2bf(tile[tc][nn]);
    }
}

// ---------------------------------------------------------------------------
// R21: faithful m201-style 8-phase 256x256 GEMM (one template, both GEMMs).
// 8 waves = 2M x 4N; wave output 128x64 (8 rg x 4 cg of 16x16); BK=64;
// K = 512 -> 8 K-tiles; LDS = 2 dbuf x (A 32KB + B 32KB) = 128 KB.
//
// Phase = { ds_read frag subtile | stage ONE half-tile (2 gll) } -> barrier
//         -> lgkmcnt(0)+sched_barrier -> setprio(1) -> 16 MFMA -> setprio(0)
//         -> [vmcnt at ph4] -> barrier.            (T3+T4+T5, 2 bar/phase)
// Quadrants: ph1 (rg0-3,cg0-1) rdA(0-3)+rdB(0-1); ph2 (rg0-3,cg2-3) rdB(2-3);
//            ph3 (rg4-7,cg2-3) rdA(4-7);          ph4 (rg4-7,cg0-1) no reads
//            (B fully register-held: bF[8]; A half-held: aF[8]).
// Stage stream during tile u (half-tile = 128 rows, 2 gll):
//   ph1: A-h1(u+1)->NXT   [NXT dead since end of u-1]
//   ph2: B-h1(u+1)->NXT
//   ph3: B-h0(u+2)->CUR   [B(u) fully read at ph2; barrier separates]
//   ph4: A-h0(u+2)->CUR   [A(u) fully read at ph3; barrier separates]
// Ledger: end-of-tile vmcnt(4) leaves only ph3+ph4 stages (4 gll, tile u+2
// h0) in flight => ALL of tile u+1's halves landed; barrier publishes.
// Never drains to 0 until tile 6 (tail). Prologue: t0 full (8 gll) + t1 h0
// (4 gll), vmcnt(4) => t0 landed. Tile6: stages t7-h1 only, ends vmcnt(0).
// Swizzle (session-verified, conflicts=0 in R6/R20): LDS slot s of row r
// holds source k-sub s^(r&7); reads at slot (kh*4+quad)^(l16&7) = 2-way
// spread (free, m136); staging pre-swizzles the per-lane global source.
// MFMA as mfma(b, a, acc): lane&15 -> C row, quad*4+reg -> C col [R9].
// ---------------------------------------------------------------------------
template<bool USE_MASK, bool OUT_F32>
__global__ __launch_bounds__(512, 2) void gemm_8ph(
    const u16* __restrict__ A, int lda,   // M x lda, reads k-cols [0,512)
    const u16* __restrict__ Bt,           // N x 512 row-major
    const float* __restrict__ bias0, const float* __restrict__ bias1,
    const float* __restrict__ amask,
    void* __restrict__ Cc, int N)
{
    __shared__ __align__(16) u16 A0[256 * 64];   // 32 KB each
    __shared__ __align__(16) u16 A1[256 * 64];
    __shared__ __align__(16) u16 B0[256 * 64];
    __shared__ __align__(16) u16 B1[256 * 64];

    const int tid  = threadIdx.x;
    const int wave = tid >> 6;
    const int lane = tid & 63;
    const int quad = lane >> 4;
    const int l16  = lane & 15;
    const int wr   = wave >> 2;        // 0..1 (row half)
    const int wc   = wave & 3;         // 0..3 (col quarter)
    const int row0 = blockIdx.x * 256;
    const int col0 = blockIdx.y * 256;

    f32x4 acc[8][4] = {};              // [rg][cg]
    bf16x8 aF[8], bF[8];               // aF: rg(half) x kh; bF: cg x kh

    // staging: chunk = tid within an 8KB (64-row) block; row = tid>>3,
    // slot tid&7 holds source sub (tid&7)^(row&7) (involution).
    const int rowi = tid >> 3;
    const int subx = (tid & 7) ^ (rowi & 7);
    const u16* Ag = A  + (size_t)(row0 + rowi) * lda + subx * 8;
    const u16* Bg = Bt + (size_t)(col0 + rowi) * 512 + subx * 8;

    const int sk0  = ((0 + quad) ^ (l16 & 7)) * 8;   // kh=0
    const int sk1  = ((4 + quad) ^ (l16 & 7)) * 8;   // kh=1
    const int arow = (wr * 128 + l16) * 64;          // rg=0 base (u16)
    const int brow = (wc * 64  + l16) * 64;          // cg=0 base (u16)

#define STG_A(BUF, HALF, KT) do {                                             \
    gll16(Ag + (size_t)((HALF)*128     ) * lda + (KT)*64,                     \
          &BUF[(HALF)*8192        + wave*512]);                               \
    gll16(Ag + (size_t)((HALF)*128 + 64) * lda + (KT)*64,                     \
          &BUF[(HALF)*8192 + 4096 + wave*512]);                               \
} while (0)
#define STG_B(BUF, HALF, KT) do {                                             \
    gll16(Bg + (size_t)((HALF)*128     ) * 512 + (KT)*64,                     \
          &BUF[(HALF)*8192        + wave*512]);                               \
    gll16(Bg + (size_t)((HALF)*128 + 64) * 512 + (KT)*64,                     \
          &BUF[(HALF)*8192 + 4096 + wave*512]);                               \
} while (0)

#define RDA_(BUF, BASE) do { _Pragma("unroll")                                \
    for (int rg = 0; rg < 4; rg++) {                                          \
        aF[rg*2  ] = *(const bf16x8*)&BUF[arow + ((BASE)+rg)*1024 + sk0];     \
        aF[rg*2+1] = *(const bf16x8*)&BUF[arow + ((BASE)+rg)*1024 + sk1];     \
    } } while (0)
#define RDB_(BUF, BASE) do { _Pragma("unroll")                                \
    for (int cg = 0; cg < 2; cg++) {                                          \
        bF[((BASE)+cg)*2  ] = *(const bf16x8*)&BUF[brow + ((BASE)+cg)*1024 + sk0]; \
        bF[((BASE)+cg)*2+1] = *(const bf16x8*)&BUF[brow + ((BASE)+cg)*1024 + sk1]; \
    } } while (0)
#define MMQ(RB, CB) do { _Pragma("unroll")                                    \
    for (int rg = 0; rg < 4; rg++) _Pragma("unroll")                          \
    for (int cg = 0; cg < 2; cg++) {                                          \
        acc[(RB)+rg][(CB)+cg] = __builtin_amdgcn_mfma_f32_16x16x32_bf16(      \
            bF[((CB)+cg)*2  ], aF[rg*2  ], acc[(RB)+rg][(CB)+cg], 0, 0, 0);   \
        acc[(RB)+rg][(CB)+cg] = __builtin_amdgcn_mfma_f32_16x16x32_bf16(      \
            bF[((CB)+cg)*2+1], aF[rg*2+1], acc[(RB)+rg][(CB)+cg], 0, 0, 0);   \
    } } while (0)

#define BARR __builtin_amdgcn_s_barrier()
#define NOP_ ((void)0)
#define W4 asm volatile("s_waitcnt vmcnt(4)" ::: "memory")
#define W0 asm volatile("s_waitcnt vmcnt(0)" ::: "memory")
#define PH(RD, ST, MM, WK) do {                                               \
    RD; ST; BARR;                                                             \
    asm volatile("s_waitcnt lgkmcnt(0)" ::: "memory");                        \
    __builtin_amdgcn_sched_barrier(0);                                        \
    __builtin_amdgcn_s_setprio(1); MM; __builtin_amdgcn_s_setprio(0);         \
    WK; BARR;                                                                 \
} while (0)

// one K-tile u: CUR=(CA,CB)=buf u%2, NXT=buf (u+1)%2.
// KT1 = k-tile index u+1, KT2 = u+2. D12/D34 gate the two stage streams.
#define TIL(CA, CB, NA, NB, KT1, KT2, D12, D34, WKE) do {                     \
    PH(RDA_(CA,0); RDB_(CB,0), if (D12) STG_A(NA,1,KT1), MMQ(0,0), NOP_);     \
    PH(RDB_(CB,2),             if (D12) STG_B(NB,1,KT1), MMQ(0,2), NOP_);     \
    PH(RDA_(CA,4),             if (D34) STG_B(CB,0,KT2), MMQ(4,2), NOP_);     \
    PH(NOP_,                   if (D34) STG_A(CA,0,KT2), MMQ(4,0), WKE);      \
} while (0)

    // prologue: t0 full (8 gll) + t1 h0 (4 gll); vmcnt(4) -> t0 landed
    STG_A(A0, 0, 0); STG_A(A0, 1, 0); STG_B(B0, 0, 0); STG_B(B0, 1, 0);
    STG_A(A1, 0, 1); STG_B(B1, 0, 1);
    W4; BARR;

    TIL(A0, B0, A1, B1, 1, 2, 1, 1, W4);   // u0
    TIL(A1, B1, A0, B0, 2, 3, 1, 1, W4);   // u1
    TIL(A0, B0, A1, B1, 3, 4, 1, 1, W4);   // u2
    TIL(A1, B1, A0, B0, 4, 5, 1, 1, W4);   // u3
    TIL(A0, B0, A1, B1, 5, 6, 1, 1, W4);   // u4
    TIL(A1, B1, A0, B0, 6, 7, 1, 1, W4);   // u5
    TIL(A0, B0, A1, B1, 7, 0, 1, 0, W0);   // u6: stage t7-h1; drain
    TIL(A1, B1, A0, B0, 0, 0, 0, 0, NOP_); // u7
#undef TIL
#undef PH
#undef STG_A
#undef STG_B
#undef RDA_
#undef RDB_
#undef MMQ

    // epilogue: bias (+mask), register-direct vector stores
    #pragma unroll
    for (int rg = 0; rg < 8; rg++) {
        const int row = row0 + wr * 128 + rg * 16 + l16;
        float mval = 1.f;
        if (USE_MASK) mval = amask[row];
        #pragma unroll
        for (int cg = 0; cg < 4; cg++) {
            const int colb = col0 + wc * 64 + cg * 16 + quad * 4;
            float4 bv = (colb < 512) ? *(const float4*)(bias0 + colb)
                                     : *(const float4*)(bias1 + colb - 512);
            f32x4 v = acc[rg][cg];
            float v0 = v[0] + bv.x, v1 = v[1] + bv.y,
                  v2 = v[2] + bv.z, v3 = v[3] + bv.w;
            if (USE_MASK) { v0 *= mval; v1 *= mval; v2 *= mval; v3 *= mval; }
            if (OUT_F32) {
                float4 o = make_float4(v0, v1, v2, v3);
                *(float4*)((float*)Cc + (size_t)row * N + colb) = o;
            } else {
                union { uint2 u; u16 s[4]; } o;
                o.s[0] = f2bf(v0); o.s[1] = f2bf(v1);
                o.s[2] = f2bf(v2); o.s[3] = f2bf(v3);
                *(uint2*)((u16*)Cc + (size_t)row * N + colb) = o.u;
            }
        }
    }
}

// ---------------------------------------------------------------------------
// R19 attn (proven): 4 lanes per (t,h), 64 t-rows/block, qf[16]/o[16] per
// lane, intra-quad shfl_xor QK reduce, conflict-free [j][78] LDS.
// ---------------------------------------------------------------------------
__global__ __launch_bounds__(256) void attn_win4(u16* __restrict__ qkv,
                                                 const float* __restrict__ bkv)
{
    __shared__ uint4 klds[8 * 78];
    __shared__ uint4 vlds[8 * 78];

    const int tid = threadIdx.x;
    const int bid = blockIdx.x;
    const int h  = bid & 7;
    const int b  = (bid >> 3) & 3;
    const int tb = bid >> 5;
    const int t0 = tb * 64;

    #pragma unroll
    for (int i = 0; i < 3; i++) {
        int idx = i * 256 + tid;
        if (idx < 624) {
            int row = idx >> 3;
            int j   = idx & 7;
            int tt  = t0 - 7 + row;
            uint4 kc, vc;
            if ((unsigned)tt < (unsigned)T_) {
                const u16* g = qkv + ((size_t)b * T_ + tt) * NQKV + 512 + h * 64 + j * 8;
                kc = *(const uint4*)g;
                vc = *(const uint4*)(g + 512);
            } else {
                union { uint4 u; u16 s[8]; } pk, pv;
                #pragma unroll
                for (int e = 0; e < 8; e++) {
                    pk.s[e] = f2bf(bkv[h * 64 + j * 8 + e]);
                    pv.s[e] = f2bf(bkv[512 + h * 64 + j * 8 + e]);
                }
                kc = pk.u; vc = pv.u;
            }
            klds[j * 78 + row] = kc;
            vlds[j * 78 + row] = vc;
        }
    }
    __syncthreads();

    const int tl = tid >> 2;
    const int ql = tid & 3;
    u16* qrow = qkv + ((size_t)b * T_ + t0 + tl) * NQKV + h * 64 + ql * 16;

    float qf[16];
    #pragma unroll
    for (int jj = 0; jj < 2; jj++) {
        union { uint4 u; u16 s[8]; } t;
        t.u = *(const uint4*)(qrow + jj * 8);
        #pragma unroll
        for (int e = 0; e < 8; e++) qf[jj * 8 + e] = bf2f(t.s[e]);
    }

    const float scale = 0.042313283f;   // ln(15)/64
    float s[WIN_];
    #pragma unroll
    for (int w = 0; w < WIN_; w++) {
        float acc = 0.f;
        #pragma unroll
        for (int jj = 0; jj < 2; jj++) {
            union { uint4 u; u16 e[8]; } kc;
            kc.u = klds[(ql * 2 + jj) * 78 + tl + w];
            #pragma unroll
            for (int e2 = 0; e2 < 8; e2++)
                acc += qf[jj * 8 + e2] * bf2f(kc.e[e2]);
        }
        acc += __shfl_xor(acc, 1, 64);
        acc += __shfl_xor(acc, 2, 64);
        s[w] = acc * scale;
    }

    float mx = s[0];
    #pragma unroll
    for (int w = 1; w < WIN_; w++) mx = fmaxf(mx, s[w]);
    float sum = 0.f;
    #pragma unroll
    for (int w = 0; w < WIN_; w++) { s[w] = __expf(s[w] - mx); sum += s[w]; }
    const float inv = 1.0f / sum;

    float o[16] = {};
    #pragma unroll
    for (int w = 0; w < WIN_; w++) {
        const float sw = s[w] * inv;
        #pragma unroll
        for (int jj = 0; jj < 2; jj++) {
            union { uint4 u; u16 e[8]; } vc;
            vc.u = vlds[(ql * 2 + jj) * 78 + tl + w];
            #pragma unroll
            for (int e2 = 0; e2 < 8; e2++)
                o[jj * 8 + e2] += sw * bf2f(vc.e[e2]);
        }
    }

    #pragma unroll
    for (int jj = 0; jj < 2; jj++) {
        union { uint4 u; u16 e[8]; } oc;
        #pragma unroll
        for (int e2 = 0; e2 < 8; e2++) oc.e[e2] = f2bf(o[jj * 8 + e2]);
        *(uint4*)(qrow + jj * 8) = oc.u;
    }
}

// ---------------------------------------------------------------------------
// Workspace: 66 MiB total.
//   [0, 1.5Mi)    Wt_qkv (1536x512 bf16)
//   [1.5Mi, 2Mi)  Wpt    (512x512 bf16)
//   [2Mi, 18Mi)   xm     (16384x512 bf16)
//   [18Mi, 66Mi)  qkv    (16384x1536 bf16); q section reused for attn output
// ---------------------------------------------------------------------------
extern "C" void kernel_launch(void* const* d_in, const int* in_sizes, int n_in,
                              void* d_out, int out_size, void* d_ws, size_t ws_size,
                              hipStream_t stream)
{
    const float* x    = (const float*)d_in[0];
    const float* mask = (const float*)d_in[1];
    const float* Wq   = (const float*)d_in[2];
    const float* bq   = (const float*)d_in[3];
    const float* Wkv  = (const float*)d_in[4];
    const float* bkv  = (const float*)d_in[5];
    const float* Wp   = (const float*)d_in[6];
    const float* bp   = (const float*)d_in[7];
    float* out = (float*)d_out;

    char* ws = (char*)d_ws;
    u16* Wt_qkv = (u16*)(ws);
    u16* Wpt    = (u16*)(ws + (size_t)(1536 * 1024));
    u16* xm     = (u16*)(ws + (size_t)(2048 * 1024));
    u16* qkv    = (u16*)(ws + (size_t)(18 * 1024 * 1024));

    // prep: mask (4096 blocks) + weight pack (256 blocks) in one dispatch
    prep<<<4352, 256, 0, stream>>>(x, mask, xm, Wq, Wkv, Wp, Wt_qkv, Wpt);

    // GEMM1: 8-phase 256^2, grid 64x6 (gridDim.x%8==0 -> XCD A-affinity)
    dim3 g1(M_ / 256, NQKV / 256);
    gemm_8ph<false, false><<<g1, 512, 0, stream>>>(
        xm, KDIM, Wt_qkv, bq, bkv, nullptr, qkv, NQKV);

    // attn: 4 lanes per (t,h), 64 t per block -> 2048 blocks
    attn_win4<<<(T_ / 64) * B_ * H_, 256, 0, stream>>>(qkv, bkv);

    // GEMM2: same template, grid 64x2 (A = qkv cols 0..511, lda 1536)
    dim3 g2(M_ / 256, C_ / 256);
    gemm_8ph<true, true><<<g2, 512, 0, stream>>>(
        qkv, NQKV, Wpt, bp, bp, mask, out, C_);
}

// Round 11
// 180.126 us; speedup vs baseline: 1.0466x; 1.0466x over previous
//
#include <hip/hip_runtime.h>
#include <hip/hip_bf16.h>

typedef unsigned short u16;

#define B_    4
#define T_    4096
#define C_    512
#define H_    8
#define D_    64
#define WIN_  15
#define PAD_  7
#define M_    (B_*T_)      // 16384 rows
#define NQKV  1536
#define KDIM  512

typedef __bf16 bf16x8 __attribute__((ext_vector_type(8)));
typedef float  f32x4  __attribute__((ext_vector_type(4)));

__device__ __forceinline__ u16 f2bf(float f) {
    union { float f; unsigned int i; } c; c.f = f;
    unsigned int lsb = (c.i >> 16) & 1u;
    c.i += 0x7fffu + lsb;                 // round-to-nearest-even
    return (u16)(c.i >> 16);
}
__device__ __forceinline__ float bf2f(u16 u) {
    union { unsigned int i; float f; } c; c.i = ((unsigned int)u) << 16; return c.f;
}

// BK=32 swizzle for the 128^2 kernel (verified R9).
__device__ __forceinline__ int swz(int row, int sub) {
    return (row * 4 + (sub ^ ((row >> 1) & 3))) * 8;
}

// global->LDS direct DMA, 16B per lane, dest = wave-uniform base + lane*16
__device__ __forceinline__ void gll16(const void* g, void* l) {
    __builtin_amdgcn_global_load_lds(
        (const __attribute__((address_space(1))) void*)g,
        (__attribute__((address_space(3))) void*)l, 16, 0, 0);
}

// ---------------------------------------------------------------------------
// R15 pack (weights only now — R21 post-mortem: mask+convert is fused into
// GEMM1's A-staging, so the xm pass and its 64 MB round-trip are gone).
// ---------------------------------------------------------------------------
__global__ __launch_bounds__(256) void pack_weights_t(
    const float* __restrict__ Wq, const float* __restrict__ Wkv,
    const float* __restrict__ Wp,
    u16* __restrict__ Wt_qkv, u16* __restrict__ Wpt)
{
    __shared__ float tile[64][65];
    const int bid = blockIdx.x;
    const float* src; int srcld; u16* dst; int n0, k0;
    if (bid < 192) {            // Wt_qkv: n0 in [0,1536), k0 in [0,512)
        n0 = (bid % 24) * 64; k0 = (bid / 24) * 64;
        dst = Wt_qkv;
        if (n0 < 512) { src = Wq + n0;          srcld = 512;  }
        else          { src = Wkv + (n0 - 512); srcld = 1024; }
    } else {                    // Wpt
        const int b2 = bid - 192;
        n0 = (b2 % 8) * 64; k0 = (b2 / 8) * 64;
        dst = Wpt; src = Wp + n0; srcld = 512;
    }
    const int tr = threadIdx.x >> 6;   // 0..3
    const int tc = threadIdx.x & 63;
    #pragma unroll
    for (int p = 0; p < 16; p++) {
        const int kk = p * 4 + tr;
        tile[kk][tc] = src[(size_t)(k0 + kk) * srcld + tc];
    }
    __syncthreads();
    #pragma unroll
    for (int p = 0; p < 16; p++) {
        const int nn = p * 4 + tr;
        dst[(size_t)(n0 + nn) * 512 + k0 + tc] = f2bf(tile[tc][nn]);
    }
}

// ---------------------------------------------------------------------------
// R21 GEMM1: 128x128 ledger kernel (proven 45.3) with A staged DIRECTLY from
// fp32 x, fusing mask-mul + bf16 RNE convert into staging (kills the xm pass
// and its 64 MB round-trip). T14 split: A-loads (4x float4) issue at tile
// START; convert + ds_write_b128 land AFTER the MFMA block -> HBM latency
// hides under frag-reads+MFMA. LDS image identical to the gll version (same
// involution swizzle slots, read side untouched).
// Ledger (counted, never 0 in steady state): per tile, manual VMEM = 2 B-gll;
// end-of-tile s_waitcnt vmcnt(2) => B(t+1) landed (A(t+1) was ds_written at
// tile t-1 and drained by the FIFO lgkm argument; explicit lgkmcnt(0) before
// each barrier makes cross-wave ds_write visibility unconditional).
// A-loads of t+2 are compiler-tracked: the convert consumes them with a
// compiler vmcnt that skips the newer B-glls (FIFO), so the manual count is
// unaffected. WAR: buffer staged at t was last read at t-1, drained before
// t-1's closing barrier.
// MFMA as mfma(b, a, acc): lane&15 -> C row, quad*4+reg -> C col [R9].
// ---------------------------------------------------------------------------
__global__ __launch_bounds__(256) void gemm1_f32a(
    const float* __restrict__ X,      // 16384 x 512 fp32
    const float* __restrict__ mask,   // M fp32 (row mask, fused into staging)
    const u16* __restrict__ Bt,       // 1536 x 512 bf16 (pre-transposed)
    const float* __restrict__ bq, const float* __restrict__ bkv,
    u16* __restrict__ Cc)             // 16384 x 1536 bf16
{
    __shared__ __align__(16) u16 As0[128 * 32];
    __shared__ __align__(16) u16 As1[128 * 32];
    __shared__ __align__(16) u16 As2[128 * 32];
    __shared__ __align__(16) u16 Bs0[128 * 32];
    __shared__ __align__(16) u16 Bs1[128 * 32];
    __shared__ __align__(16) u16 Bs2[128 * 32];

    const int tid  = threadIdx.x;
    const int wave = tid >> 6;
    const int lane = tid & 63;
    const int row0 = blockIdx.x * 128;
    const int col0 = blockIdx.y * 128;

    const int wm = (wave >> 1) * 64;
    const int wn = (wave & 1) * 64;

    f32x4 acc[4][4] = {};

    const int quad = lane >> 4;
    const int l16  = lane & 15;

    // staging chunks (16B bf16 = 8 elems = 8 f32): cA, cB; source sub is
    // inverse-swizzled so LINEAR LDS slots give the swizzled read image.
    const int cA = wave * 128 + lane;
    const int cB = cA + 64;
    const int rA = cA >> 2, sA = (cA & 3) ^ ((rA >> 1) & 3);
    const int rB = cB >> 2, sB = (cB & 3) ^ ((rB >> 1) & 3);
    const float* AgF0 = X + (size_t)(row0 + rA) * 512 + sA * 8;
    const float* AgF1 = X + (size_t)(row0 + rB) * 512 + sB * 8;
    const u16*   Bg0  = Bt + (size_t)(col0 + rA) * 512 + sA * 8;
    const u16*   Bg1  = Bt + (size_t)(col0 + rB) * 512 + sB * 8;
    const float mvA = mask[row0 + rA];
    const float mvB = mask[row0 + rB];
    const int ldsB0 = wave * 1024;          // gll dest (wave-uniform, u16)
    const int ldsB1 = wave * 1024 + 512;
    const int ldsA0 = wave * 1024 + lane * 8;        // ds_write dest (u16)
    const int ldsA1 = wave * 1024 + 512 + lane * 8;

#define FR(BUF, R) (*(const bf16x8*)&BUF[swz((R) + l16, quad)])

#define CVT_WRITE(SA, p00, p01, p10, p11) do {                               \
    union { uint4 u; u16 s[8]; } w0, w1;                                     \
    w0.s[0] = f2bf(p00.x * mvA); w0.s[1] = f2bf(p00.y * mvA);                \
    w0.s[2] = f2bf(p00.z * mvA); w0.s[3] = f2bf(p00.w * mvA);                \
    w0.s[4] = f2bf(p01.x * mvA); w0.s[5] = f2bf(p01.y * mvA);                \
    w0.s[6] = f2bf(p01.z * mvA); w0.s[7] = f2bf(p01.w * mvA);                \
    w1.s[0] = f2bf(p10.x * mvB); w1.s[1] = f2bf(p10.y * mvB);                \
    w1.s[2] = f2bf(p10.z * mvB); w1.s[3] = f2bf(p10.w * mvB);                \
    w1.s[4] = f2bf(p11.x * mvB); w1.s[5] = f2bf(p11.y * mvB);                \
    w1.s[6] = f2bf(p11.z * mvB); w1.s[7] = f2bf(p11.w * mvB);                \
    *(uint4*)&SA[ldsA0] = w0.u;                                              \
    *(uint4*)&SA[ldsA1] = w1.u;                                              \
} while (0)

// MODE: 1 = stage tile t+2 (A fp32-fused + B gll), wait vmcnt(2);
//       0 = drain vmcnt(0); -1 = bare last tile.
#define TILE(RA, RB, SA, SB, KST, MODE)                                      \
    do {                                                                     \
        float4 p00, p01, p10, p11;                                           \
        if ((MODE) == 1) {                                                   \
            p00 = *(const float4*)(AgF0 + (KST));                            \
            p01 = *(const float4*)(AgF0 + (KST) + 4);                        \
            p10 = *(const float4*)(AgF1 + (KST));                            \
            p11 = *(const float4*)(AgF1 + (KST) + 4);                        \
            gll16(Bg0 + (KST), &SB[ldsB0]);                                  \
            gll16(Bg1 + (KST), &SB[ldsB1]);                                  \
        }                                                                    \
        bf16x8 a[4], b[4];                                                   \
        _Pragma("unroll")                                                    \
        for (int i = 0; i < 4; i++) {                                        \
            a[i] = FR(RA, wm + i * 16);                                      \
            b[i] = FR(RB, wn + i * 16);                                      \
        }                                                                    \
        __builtin_amdgcn_s_setprio(1);                                       \
        _Pragma("unroll")                                                    \
        for (int ci = 0; ci < 4; ci++)                                       \
            _Pragma("unroll")                                                \
            for (int ri = 0; ri < 4; ri++)                                   \
                acc[ci][ri] = __builtin_amdgcn_mfma_f32_16x16x32_bf16(       \
                    b[ci], a[ri], acc[ci][ri], 0, 0, 0);                     \
        __builtin_amdgcn_s_setprio(0);                                       \
        if ((MODE) == 1) CVT_WRITE(SA, p00, p01, p10, p11);                  \
        if ((MODE) == 1)      asm volatile("s_waitcnt vmcnt(2)" ::: "memory"); \
        else if ((MODE) == 0) asm volatile("s_waitcnt vmcnt(0)" ::: "memory"); \
        if ((MODE) >= 0) {                                                   \
            asm volatile("s_waitcnt lgkmcnt(0)" ::: "memory");               \
            __builtin_amdgcn_s_barrier();                                    \
        }                                                                    \
    } while (0)

    // prologue: stage tiles 0 and 1 (A fused-convert, B gll); B0 landed
    {
        float4 q00 = *(const float4*)(AgF0);
        float4 q01 = *(const float4*)(AgF0 + 4);
        float4 q10 = *(const float4*)(AgF1);
        float4 q11 = *(const float4*)(AgF1 + 4);
        float4 r00 = *(const float4*)(AgF0 + 32);
        float4 r01 = *(const float4*)(AgF0 + 36);
        float4 r10 = *(const float4*)(AgF1 + 32);
        float4 r11 = *(const float4*)(AgF1 + 36);
        gll16(Bg0,      &Bs0[ldsB0]);
        gll16(Bg1,      &Bs0[ldsB1]);
        gll16(Bg0 + 32, &Bs1[ldsB0]);
        gll16(Bg1 + 32, &Bs1[ldsB1]);
        CVT_WRITE(As0, q00, q01, q10, q11);
        CVT_WRITE(As1, r00, r01, r10, r11);
        asm volatile("s_waitcnt vmcnt(2)" ::: "memory");   // B0 landed
        asm volatile("s_waitcnt lgkmcnt(0)" ::: "memory"); // A writes visible
        __builtin_amdgcn_s_barrier();
    }

    // 16 K-tiles (K = 512): read buf t%3, stage tile t+2 -> buf (t+2)%3
    TILE(As0, Bs0, As2, Bs2,  64, 1);   // t=0
    TILE(As1, Bs1, As0, Bs0,  96, 1);   // t=1
    TILE(As2, Bs2, As1, Bs1, 128, 1);   // t=2
    TILE(As0, Bs0, As2, Bs2, 160, 1);   // t=3
    TILE(As1, Bs1, As0, Bs0, 192, 1);   // t=4
    TILE(As2, Bs2, As1, Bs1, 224, 1);   // t=5
    TILE(As0, Bs0, As2, Bs2, 256, 1);   // t=6
    TILE(As1, Bs1, As0, Bs0, 288, 1);   // t=7
    TILE(As2, Bs2, As1, Bs1, 320, 1);   // t=8
    TILE(As0, Bs0, As2, Bs2, 352, 1);   // t=9
    TILE(As1, Bs1, As0, Bs0, 384, 1);   // t=10
    TILE(As2, Bs2, As1, Bs1, 416, 1);   // t=11
    TILE(As0, Bs0, As2, Bs2, 448, 1);   // t=12
    TILE(As1, Bs1, As0, Bs0, 480, 1);   // t=13 (stages tile 15 -> buf0)
    TILE(As2, Bs2, As0, Bs0,   0, 0);   // t=14 (drain: tile 15 landed)
    TILE(As0, Bs0, As1, Bs1,   0, -1);  // t=15
#undef TILE
#undef CVT_WRITE
#undef FR

    // epilogue: bias add, bf16 pack, register-direct uint2 stores
    #pragma unroll
    for (int ri = 0; ri < 4; ri++) {
        const int row = row0 + wm + ri * 16 + l16;
        #pragma unroll
        for (int ci = 0; ci < 4; ci++) {
            const int colb = col0 + wn + ci * 16 + quad * 4;
            float4 bv = (colb < 512) ? *(const float4*)(bq + colb)
                                     : *(const float4*)(bkv + colb - 512);
            f32x4 v = acc[ci][ri];
            union { uint2 u; u16 s[4]; } o;
            o.s[0] = f2bf(v[0] + bv.x); o.s[1] = f2bf(v[1] + bv.y);
            o.s[2] = f2bf(v[2] + bv.z); o.s[3] = f2bf(v[3] + bv.w);
            *(uint2*)(Cc + (size_t)row * NQKV + colb) = o.u;
        }
    }
}

// ---------------------------------------------------------------------------
// R20 GEMM2 (proven, kept): 256x128 tile, 8 waves, BK=64, ring-3 LDS,
// single barrier per K-tile, counted vmcnt(6), 256 blocks = 1/CU fill.
// ---------------------------------------------------------------------------
__global__ __launch_bounds__(512, 2) void gemm2_256x128(
    const u16* __restrict__ A,        // qkv, 16384 x 1536 (reads cols 0..511)
    const u16* __restrict__ Bt,       // Wpt, 512 x 512
    const float* __restrict__ bp,
    const float* __restrict__ amask,
    float* __restrict__ out)          // 16384 x 512 fp32
{
    __shared__ __align__(16) u16 A0[256 * 64];   // 32 KB each
    __shared__ __align__(16) u16 A1[256 * 64];
    __shared__ __align__(16) u16 A2[256 * 64];
    __shared__ __align__(16) u16 B0[128 * 64];   // 16 KB each
    __shared__ __align__(16) u16 B1[128 * 64];
    __shared__ __align__(16) u16 B2[128 * 64];

    const int tid  = threadIdx.x;
    const int wave = tid >> 6;
    const int lane = tid & 63;
    const int quad = lane >> 4;
    const int l16  = lane & 15;
    const int row0 = blockIdx.x * 256;
    const int col0 = blockIdx.y * 128;
    const int wm = (wave >> 1) * 64;   // 4 M-groups
    const int wn = (wave & 1) * 64;    // 2 N-groups

    f32x4 acc[4][4] = {};              // [rg][cg]

    const int rowi = tid >> 3;                       // 0..63
    const int subx = (tid & 7) ^ (rowi & 7);
    const u16* Ag = A  + (size_t)(row0 + rowi) * NQKV + subx * 8;
    const u16* Bg = Bt + (size_t)(col0 + rowi) * 512  + subx * 8;
    const int so = wave * 512;                       // u16, wave-uniform

    const int aoff = (wm + l16) * 64;
    const int boff = (wn + l16) * 64;
    const int sk0 = ((0 + quad) ^ (l16 & 7)) * 8;    // kh=0 (k 0..31)
    const int sk1 = ((4 + quad) ^ (l16 & 7)) * 8;    // kh=1 (k 32..63)

#define SA_(BUF, s, KK) gll16(Ag + (size_t)(s) * 64 * NQKV + (KK), &BUF[(s) * 4096 + so])
#define SB_(BUF, s, KK) gll16(Bg + (size_t)(s) * 64 * 512  + (KK), &BUF[(s) * 4096 + so])

#define TILE2(AB, BB, SA, SB, KK, DO, WK) do {                                \
    bf16x8 aF0[4], aF1[4], bF0[4], bF1[4];                                    \
    _Pragma("unroll")                                                         \
    for (int rg = 0; rg < 4; rg++) {                                          \
        aF0[rg] = *(const bf16x8*)&AB[aoff + rg * 1024 + sk0];                \
        aF1[rg] = *(const bf16x8*)&AB[aoff + rg * 1024 + sk1];                \
    }                                                                         \
    _Pragma("unroll")                                                         \
    for (int cg = 0; cg < 4; cg++) {                                          \
        bF0[cg] = *(const bf16x8*)&BB[boff + cg * 1024 + sk0];                \
        bF1[cg] = *(const bf16x8*)&BB[boff + cg * 1024 + sk1];                \
    }                                                                         \
    if (DO) { SA_(SA, 0, KK); SA_(SA, 1, KK); SA_(SA, 2, KK); SA_(SA, 3, KK); \
              SB_(SB, 0, KK); SB_(SB, 1, KK); }                               \
    asm volatile("s_waitcnt lgkmcnt(0)" ::: "memory");                        \
    __builtin_amdgcn_sched_barrier(0);                                        \
    __builtin_amdgcn_s_setprio(1);                                            \
    _Pragma("unroll")                                                         \
    for (int rg = 0; rg < 4; rg++)                                            \
        _Pragma("unroll")                                                     \
        for (int cg = 0; cg < 4; cg++) {                                      \
            acc[rg][cg] = __builtin_amdgcn_mfma_f32_16x16x32_bf16(            \
                bF0[cg], aF0[rg], acc[rg][cg], 0, 0, 0);                      \
            acc[rg][cg] = __builtin_amdgcn_mfma_f32_16x16x32_bf16(            \
                bF1[cg], aF1[rg], acc[rg][cg], 0, 0, 0);                      \
        }                                                                     \
    __builtin_amdgcn_s_setprio(0);                                            \
    if ((WK) == 6)      asm volatile("s_waitcnt vmcnt(6)" ::: "memory");      \
    else if ((WK) == 0) asm volatile("s_waitcnt vmcnt(0)" ::: "memory");      \
    if ((WK) >= 0) __builtin_amdgcn_s_barrier();                              \
} while (0)

    SA_(A0, 0, 0);  SA_(A0, 1, 0);  SA_(A0, 2, 0);  SA_(A0, 3, 0);
    SB_(B0, 0, 0);  SB_(B0, 1, 0);
    SA_(A1, 0, 64); SA_(A1, 1, 64); SA_(A1, 2, 64); SA_(A1, 3, 64);
    SB_(B1, 0, 64); SB_(B1, 1, 64);
    asm volatile("s_waitcnt vmcnt(6)" ::: "memory");
    __builtin_amdgcn_s_barrier();

    TILE2(A0, B0, A2, B2, 128, 1, 6);   // t0 stages t2
    TILE2(A1, B1, A0, B0, 192, 1, 6);   // t1 stages t3
    TILE2(A2, B2, A1, B1, 256, 1, 6);   // t2 stages t4
    TILE2(A0, B0, A2, B2, 320, 1, 6);   // t3 stages t5
    TILE2(A1, B1, A0, B0, 384, 1, 6);   // t4 stages t6
    TILE2(A2, B2, A1, B1, 448, 1, 6);   // t5 stages t7
    TILE2(A0, B0, A1, B1,   0, 0, 0);   // t6 (drain: t7 landed)
    TILE2(A1, B1, A2, B2,   0, 0, -1);  // t7
#undef TILE2
#undef SA_
#undef SB_

    #pragma unroll
    for (int rg = 0; rg < 4; rg++) {
        const int row = row0 + wm + rg * 16 + l16;
        const float mval = amask[row];
        #pragma unroll
        for (int cg = 0; cg < 4; cg++) {
            const int colb = col0 + wn + cg * 16 + quad * 4;
            float4 bv = *(const float4*)(bp + colb);
            f32x4 v = acc[rg][cg];
            float4 o = make_float4((v[0] + bv.x) * mval, (v[1] + bv.y) * mval,
                                   (v[2] + bv.z) * mval, (v[3] + bv.w) * mval);
            *(float4*)(out + (size_t)row * 512 + colb) = o;
        }
    }
}

// ---------------------------------------------------------------------------
// R19 attn (proven): 4 lanes per (t,h), 64 t-rows/block, qf[16]/o[16] per
// lane, intra-quad shfl_xor QK reduce, conflict-free [j][78] LDS.
// ---------------------------------------------------------------------------
__global__ __launch_bounds__(256) void attn_win4(u16* __restrict__ qkv,
                                                 const float* __restrict__ bkv)
{
    __shared__ uint4 klds[8 * 78];
    __shared__ uint4 vlds[8 * 78];

    const int tid = threadIdx.x;
    const int bid = blockIdx.x;
    const int h  = bid & 7;
    const int b  = (bid >> 3) & 3;
    const int tb = bid >> 5;
    const int t0 = tb * 64;

    #pragma unroll
    for (int i = 0; i < 3; i++) {
        int idx = i * 256 + tid;
        if (idx < 624) {
            int row = idx >> 3;
            int j   = idx & 7;
            int tt  = t0 - 7 + row;
            uint4 kc, vc;
            if ((unsigned)tt < (unsigned)T_) {
                const u16* g = qkv + ((size_t)b * T_ + tt) * NQKV + 512 + h * 64 + j * 8;
                kc = *(const uint4*)g;
                vc = *(const uint4*)(g + 512);
            } else {
                union { uint4 u; u16 s[8]; } pk, pv;
                #pragma unroll
                for (int e = 0; e < 8; e++) {
                    pk.s[e] = f2bf(bkv[h * 64 + j * 8 + e]);
                    pv.s[e] = f2bf(bkv[512 + h * 64 + j * 8 + e]);
                }
                kc = pk.u; vc = pv.u;
            }
            klds[j * 78 + row] = kc;
            vlds[j * 78 + row] = vc;
        }
    }
    __syncthreads();

    const int tl = tid >> 2;
    const int ql = tid & 3;
    u16* qrow = qkv + ((size_t)b * T_ + t0 + tl) * NQKV + h * 64 + ql * 16;

    float qf[16];
    #pragma unroll
    for (int jj = 0; jj < 2; jj++) {
        union { uint4 u; u16 s[8]; } t;
        t.u = *(const uint4*)(qrow + jj * 8);
        #pragma unroll
        for (int e = 0; e < 8; e++) qf[jj * 8 + e] = bf2f(t.s[e]);
    }

    const float scale = 0.042313283f;   // ln(15)/64
    float s[WIN_];
    #pragma unroll
    for (int w = 0; w < WIN_; w++) {
        float acc = 0.f;
        #pragma unroll
        for (int jj = 0; jj < 2; jj++) {
            union { uint4 u; u16 e[8]; } kc;
            kc.u = klds[(ql * 2 + jj) * 78 + tl + w];
            #pragma unroll
            for (int e2 = 0; e2 < 8; e2++)
                acc += qf[jj * 8 + e2] * bf2f(kc.e[e2]);
        }
        acc += __shfl_xor(acc, 1, 64);
        acc += __shfl_xor(acc, 2, 64);
        s[w] = acc * scale;
    }

    float mx = s[0];
    #pragma unroll
    for (int w = 1; w < WIN_; w++) mx = fmaxf(mx, s[w]);
    float sum = 0.f;
    #pragma unroll
    for (int w = 0; w < WIN_; w++) { s[w] = __expf(s[w] - mx); sum += s[w]; }
    const float inv = 1.0f / sum;

    float o[16] = {};
    #pragma unroll
    for (int w = 0; w < WIN_; w++) {
        const float sw = s[w] * inv;
        #pragma unroll
        for (int jj = 0; jj < 2; jj++) {
            union { uint4 u; u16 e[8]; } vc;
            vc.u = vlds[(ql * 2 + jj) * 78 + tl + w];
            #pragma unroll
            for (int e2 = 0; e2 < 8; e2++)
                o[jj * 8 + e2] += sw * bf2f(vc.e[e2]);
        }
    }

    #pragma unroll
    for (int jj = 0; jj < 2; jj++) {
        union { uint4 u; u16 e[8]; } oc;
        #pragma unroll
        for (int e2 = 0; e2 < 8; e2++) oc.e[e2] = f2bf(o[jj * 8 + e2]);
        *(uint4*)(qrow + jj * 8) = oc.u;
    }
}

// ---------------------------------------------------------------------------
// Workspace: 66 MiB total.
//   [0, 1.5Mi)    Wt_qkv (1536x512 bf16)
//   [1.5Mi, 2Mi)  Wpt    (512x512 bf16)
//   [2Mi, 18Mi)   (free — xm eliminated in R21)
//   [18Mi, 66Mi)  qkv    (16384x1536 bf16); q section reused for attn output
// ---------------------------------------------------------------------------
extern "C" void kernel_launch(void* const* d_in, const int* in_sizes, int n_in,
                              void* d_out, int out_size, void* d_ws, size_t ws_size,
                              hipStream_t stream)
{
    const float* x    = (const float*)d_in[0];
    const float* mask = (const float*)d_in[1];
    const float* Wq   = (const float*)d_in[2];
    const float* bq   = (const float*)d_in[3];
    const float* Wkv  = (const float*)d_in[4];
    const float* bkv  = (const float*)d_in[5];
    const float* Wp   = (const float*)d_in[6];
    const float* bp   = (const float*)d_in[7];
    float* out = (float*)d_out;

    char* ws = (char*)d_ws;
    u16* Wt_qkv = (u16*)(ws);
    u16* Wpt    = (u16*)(ws + (size_t)(1536 * 1024));
    u16* qkv    = (u16*)(ws + (size_t)(18 * 1024 * 1024));

    // pack: weights only (mask+convert now fused into GEMM1 staging)
    pack_weights_t<<<256, 256, 0, stream>>>(Wq, Wkv, Wp, Wt_qkv, Wpt);

    // GEMM1: 128^2 ledger kernel with fp32-A fused mask+convert staging
    dim3 g1(M_ / 128, NQKV / 128);
    gemm1_f32a<<<g1, 256, 0, stream>>>(x, mask, Wt_qkv, bq, bkv, qkv);

    // attn: 4 lanes per (t,h), 64 t per block -> 2048 blocks
    attn_win4<<<(T_ / 64) * B_ * H_, 256, 0, stream>>>(qkv, bkv);

    // GEMM2: 256x128 single-barrier-per-tile kernel, 256 blocks = 1/CU
    dim3 g2(M_ / 256, C_ / 128);
    gemm2_256x128<<<g2, 512, 0, stream>>>(qkv, Wpt, bp, mask, out);
}